// Round 3
// baseline (147.441 us; speedup 1.0000x reference)
//
#include <hip/hip_runtime.h>

#define NROWS 2048
#define KDIM  768
#define L     40
#define KCH   6          // K-chunks (768 = 6 * 128), split across blockIdx.y
#define KCSZ  128
#define HN    (NROWS * L)

// v_add_f32 with DPP cross-lane source; all sources valid so bound_ctrl moot.
#define DPP_ADD(s, ctrl) \
    ((s) + __int_as_float(__builtin_amdgcn_update_dpp(0, __float_as_int(s), (ctrl), 0xF, 0xF, true)))

// ---------------------------------------------------------------------------
// Kernel 1: projections, K split 6-way across blocks, DPP in-wave reduction,
// atomic accumulate into zero-initialized hxb / hy. No LDS, no barrier.
// block 256 = 16 rows x 16 segs; wave = 4 rows x 16 segs, seg-group == DPP row.
// Reduction over 16 segs: xor1 (quad_perm 0xB1), xor2 (quad_perm 0x4E),
// xor4 (row_half_mirror 0x141, valid on quad-uniform values),
// xor8 (row_mirror 0x140, valid on oct-uniform values). All VALU-pipe.
// ---------------------------------------------------------------------------
__global__ __launch_bounds__(256) void k_proj(const float* __restrict__ x,
                                              const float* __restrict__ y,
                                              const float* __restrict__ W1,
                                              float* __restrict__ hxb,
                                              float* __restrict__ hy) {
    const int kc    = blockIdx.y;
    const int which = blockIdx.z;
    const float* __restrict__ A = which ? y : x;
    float* __restrict__ out = which ? hy : hxb;
    const int tid = threadIdx.x;
    const int r   = tid >> 4;    // 0..15 row within block
    const int seg = tid & 15;    // 0..15 K-segment (8 floats each)
    const int row = blockIdx.x * 16 + r;

    // this thread's 8 A elements: k = kc*128 + {seg*4..+3, 64+seg*4..+3}
    const float* arow = A + (size_t)row * KDIM + kc * KCSZ;
    float4 a0 = *(const float4*)(arow + seg * 4);
    float4 a1 = *(const float4*)(arow + 64 + seg * 4);

    const float* wbase = W1 + (size_t)which * KDIM + kc * KCSZ;
    float* orow = out + (size_t)row * L;
#pragma unroll 8
    for (int o = 0; o < L; ++o) {
        const float* wrow = wbase + (size_t)o * (2 * KDIM);
        float4 w0 = *(const float4*)(wrow + seg * 4);
        float4 w1 = *(const float4*)(wrow + 64 + seg * 4);
        float s = a0.x * w0.x + a0.y * w0.y + a0.z * w0.z + a0.w * w0.w
                + a1.x * w1.x + a1.y * w1.y + a1.z * w1.z + a1.w * w1.w;
        s = DPP_ADD(s, 0xB1);    // + lane^1
        s = DPP_ADD(s, 0x4E);    // + lane^2  -> quad sums
        s = DPP_ADD(s, 0x141);   // + other quad in oct -> oct sums
        s = DPP_ADD(s, 0x140);   // + other oct in row  -> full 16-seg sum
        if (seg == 0) atomicAdd(orow + o, s);
    }
}

// ---------------------------------------------------------------------------
// Kernel 2: pairwise sum of exp(T_ij - 1) + diagonal T0 sum.
//   acc_ij = sum_k relu(hy[i,k] + hxb[j,k] + b1[k]) * W2[k]
//   (b1 folded into the shx staging since hxb is atomic-accumulated from 0)
//   sumExp += exp(acc_ij + b2 - 1);  if (i==j) sumT0 += acc_ij + b2
// Tile BI=128 x BJ=64, block 256 = 16(ty) x 16(tx), micro-tile 8x4,
// lane-interleaved rows: i = i0+ty+16u, j = j0+tx+16v. LDS stride 44.
// ---------------------------------------------------------------------------
#define BI 128
#define BJ 64
#define STRD 44

__global__ __launch_bounds__(256) void k_pair(const float* __restrict__ hxb,
                                              const float* __restrict__ hy,
                                              const float* __restrict__ W2,
                                              const float* __restrict__ b1,
                                              const float* __restrict__ b2p,
                                              float* __restrict__ sums) {
    __shared__ float shy[BI * STRD];
    __shared__ float shx[BJ * STRD];
    __shared__ float sw2[STRD];
    __shared__ float red[8];

    const int tid = threadIdx.x;
    const int i0 = blockIdx.x * BI;
    const int j0 = blockIdx.y * BJ;

    for (int idx = tid; idx < BI * 10; idx += 256) {
        int rr = idx / 10, c = idx - rr * 10;
        float4 v = ((const float4*)(hy + (size_t)i0 * L))[idx];
        *(float4*)(shy + rr * STRD + c * 4) = v;
    }
    for (int idx = tid; idx < BJ * 10; idx += 256) {
        int rr = idx / 10, c = idx - rr * 10;
        float4 v = ((const float4*)(hxb + (size_t)j0 * L))[idx];
        float4 bv = ((const float4*)b1)[c];
        v.x += bv.x; v.y += bv.y; v.z += bv.z; v.w += bv.w;
        *(float4*)(shx + rr * STRD + c * 4) = v;
    }
    if (tid < 10) ((float4*)sw2)[tid] = ((const float4*)W2)[tid];
    __syncthreads();

    const int tx = tid & 15, ty = tid >> 4;

    float acc[8][4];
#pragma unroll
    for (int u = 0; u < 8; ++u)
#pragma unroll
        for (int v = 0; v < 4; ++v) acc[u][v] = 0.f;

#pragma unroll
    for (int k4 = 0; k4 < 10; ++k4) {
        float4 w = *(const float4*)(sw2 + k4 * 4);
        float4 ay[8], ax[4];
#pragma unroll
        for (int u = 0; u < 8; ++u)
            ay[u] = *(const float4*)(shy + (ty + 16 * u) * STRD + k4 * 4);
#pragma unroll
        for (int v = 0; v < 4; ++v)
            ax[v] = *(const float4*)(shx + (tx + 16 * v) * STRD + k4 * 4);
#pragma unroll
        for (int u = 0; u < 8; ++u)
#pragma unroll
            for (int v = 0; v < 4; ++v) {
                float t;
                t = ay[u].x + ax[v].x; t = fmaxf(t, 0.f); acc[u][v] += t * w.x;
                t = ay[u].y + ax[v].y; t = fmaxf(t, 0.f); acc[u][v] += t * w.y;
                t = ay[u].z + ax[v].z; t = fmaxf(t, 0.f); acc[u][v] += t * w.z;
                t = ay[u].w + ax[v].w; t = fmaxf(t, 0.f); acc[u][v] += t * w.w;
            }
    }

    const float b2v = b2p[0];
    float sumE = 0.f, sumT = 0.f;
#pragma unroll
    for (int u = 0; u < 8; ++u)
#pragma unroll
        for (int v = 0; v < 4; ++v) {
            int gi = i0 + ty + 16 * u;
            int gj = j0 + tx + 16 * v;
            float val = acc[u][v] + b2v;
            if (gi == gj) sumT += val;
            sumE += __expf(val - 1.f);
        }

#pragma unroll
    for (int off = 32; off > 0; off >>= 1) {
        sumE += __shfl_down(sumE, off);
        sumT += __shfl_down(sumT, off);
    }
    int wid = tid >> 6;
    if ((tid & 63) == 0) { red[wid] = sumE; red[4 + wid] = sumT; }
    __syncthreads();
    if (tid == 0) {
        float e = red[0] + red[1] + red[2] + red[3];
        float t = red[4] + red[5] + red[6] + red[7];
        atomicAdd(&sums[1], e);
        atomicAdd(&sums[0], t);
    }
}

// ---------------------------------------------------------------------------
// Kernel 3: lower_bound = sumT0/N - sumExp/N^2
// ---------------------------------------------------------------------------
__global__ void k_fin(const float* __restrict__ sums, float* __restrict__ out) {
    const float invN = 1.0f / (float)NROWS;
    out[0] = sums[0] * invN - sums[1] * invN * invN;
}

extern "C" void kernel_launch(void* const* d_in, const int* in_sizes, int n_in,
                              void* d_out, int out_size, void* d_ws, size_t ws_size,
                              hipStream_t stream) {
    const float* x  = (const float*)d_in[0];
    const float* y  = (const float*)d_in[1];
    const float* W1 = (const float*)d_in[2];
    const float* b1 = (const float*)d_in[3];
    const float* W2 = (const float*)d_in[4];
    const float* b2 = (const float*)d_in[5];
    float* out = (float*)d_out;

    float* wsf  = (float*)d_ws;
    float* sums = wsf;                   // [0]=sumT0, [1]=sumExp
    float* hxb  = wsf + 16;              // 2048*40, atomic-accumulated
    float* hy   = hxb + HN;              // 2048*40, atomic-accumulated

    // one fill zeroes sums + hxb + hy (contiguous)
    hipMemsetAsync(sums, 0, (16 + 2 * HN) * sizeof(float), stream);
    k_proj<<<dim3(NROWS / 16, KCH, 2), 256, 0, stream>>>(x, y, W1, hxb, hy);
    k_pair<<<dim3(NROWS / BI, NROWS / BJ), 256, 0, stream>>>(hxb, hy, W2, b1, b2, sums);
    k_fin<<<1, 1, 0, stream>>>(sums, out);
}

// Round 4
// 119.452 us; speedup vs baseline: 1.2343x; 1.2343x over previous
//
#include <hip/hip_runtime.h>

#define NROWS 2048
#define KDIM  768
#define L     40
#define KC    96          // K per chunk; 768 = 8 * 96
#define NKC   8
#define HN    (NROWS * L)
#define NPAIRBLK 512      // k_pair grid size (16 x 32)

// ---------------------------------------------------------------------------
// Kernel 1: partial projections, register-blocked.
// grid (64 rowblocks, 8 kchunks), block 256 = 64 rows(lanes) x 4 waves.
// Each wave owns 10 outputs (o-group, wave-uniform via readfirstlane -> W
// loads become s_load on the scalar pipe). A-chunk (64 rows x 96 k) staged in
// LDS transposed + xor-swizzled: both staging writes and per-k reads are
// bank-conflict-free. Per k: 1 ds_read_b32 + 10 v_fmac (SGPR w operand).
// Partials written [kc][o][row] -> fully coalesced 256B stores.
// ---------------------------------------------------------------------------
__global__ __launch_bounds__(256) void k_proj(const float* __restrict__ x,
                                              const float* __restrict__ y,
                                              const float* __restrict__ W1,
                                              float* __restrict__ part) {
    __shared__ float shA[KC * 64];          // 24 KB, [k][row^((k>>2)&31)]
    const int tid = threadIdx.x;
    const int rb  = blockIdx.x;             // 0..63 (0-31: x, 32-63: y)
    const int kc  = blockIdx.y;             // 0..7
    const int k0  = kc * KC;
    const int which = rb >> 5;
    const float* __restrict__ A = which ? y : x;
    const int r0 = (rb & 31) * 64;

    // stage: 1536 float4 = 6 per thread, coalesced global reads
#pragma unroll
    for (int p = 0; p < 6; ++p) {
        int idx = tid + p * 256;
        int row = idx / 24;
        int kk4 = idx - row * 24;           // 0..23
        float4 v = *(const float4*)(A + (size_t)(r0 + row) * KDIM + k0 + kk4 * 4);
        int rowx = row ^ kk4;               // xor swizzle, kk4 < 32
        shA[(kk4 * 4 + 0) * 64 + rowx] = v.x;
        shA[(kk4 * 4 + 1) * 64 + rowx] = v.y;
        shA[(kk4 * 4 + 2) * 64 + rowx] = v.z;
        shA[(kk4 * 4 + 3) * 64 + rowx] = v.w;
    }
    __syncthreads();

    const int row = tid & 63;
    const int og  = __builtin_amdgcn_readfirstlane(tid >> 6);   // wave-uniform
    const float* wbase = W1 + (size_t)which * KDIM
                            + (size_t)(og * 10) * (2 * KDIM) + k0;

    float acc[10];
#pragma unroll
    for (int oi = 0; oi < 10; ++oi) acc[oi] = 0.f;

#pragma unroll
    for (int k4 = 0; k4 < 24; ++k4) {
        int rowx = row ^ k4;
        float a0 = shA[(k4 * 4 + 0) * 64 + rowx];
        float a1 = shA[(k4 * 4 + 1) * 64 + rowx];
        float a2 = shA[(k4 * 4 + 2) * 64 + rowx];
        float a3 = shA[(k4 * 4 + 3) * 64 + rowx];
#pragma unroll
        for (int oi = 0; oi < 10; ++oi) {
            float4 w = *(const float4*)(wbase + (size_t)oi * (2 * KDIM) + k4 * 4);
            acc[oi] += a0 * w.x + a1 * w.y + a2 * w.z + a3 * w.w;
        }
    }

    // part[(kc*40 + o) * 4096 + rb*64 + row], coalesced per oi
    float* po = part + ((size_t)kc * L + og * 10) * 4096 + rb * 64 + row;
#pragma unroll
    for (int oi = 0; oi < 10; ++oi) po[(size_t)oi * 4096] = acc[oi];
}

// ---------------------------------------------------------------------------
// Kernel 1b: reduce 8 K-chunk partials -> hxb (x-proj) / hy (y-proj).
// 64 blocks; block rb covers rows rb*64..+63, all 40 outputs.
// Coalesced partial reads; LDS transpose (stride 41) for coalesced writes.
// Block 0 also zeroes sums + finalize ticket (replaces memset node).
// ---------------------------------------------------------------------------
__global__ __launch_bounds__(256) void k_red(const float* __restrict__ part,
                                             float* __restrict__ hxb,
                                             float* __restrict__ hy,
                                             float* __restrict__ sums) {
    __shared__ float shT[64 * 41];
    const int tid = threadIdx.x;
    const int rb  = blockIdx.x;             // 0..63
    if (rb == 0 && tid == 0) {
        sums[0] = 0.f; sums[1] = 0.f;
        ((unsigned*)sums)[2] = 0u;          // finalize ticket
    }
    const int row = tid & 63;
    const int og  = tid >> 6;

    float s[10];
#pragma unroll
    for (int oi = 0; oi < 10; ++oi) s[oi] = 0.f;
    const float* pb = part + (size_t)(og * 10) * 4096 + rb * 64 + row;
#pragma unroll
    for (int kc = 0; kc < NKC; ++kc)
#pragma unroll
        for (int oi = 0; oi < 10; ++oi)
            s[oi] += pb[((size_t)kc * L + oi) * 4096];

#pragma unroll
    for (int oi = 0; oi < 10; ++oi) shT[row * 41 + og * 10 + oi] = s[oi];
    __syncthreads();

    float* out = (rb < 32) ? (hxb + (size_t)rb * 64 * L)
                           : (hy  + (size_t)(rb - 32) * 64 * L);
    for (int idx = tid; idx < 64 * L; idx += 256) {
        int r = idx / L, o = idx - r * L;
        out[idx] = shT[r * 41 + o];
    }
}

// ---------------------------------------------------------------------------
// Kernel 2: pairwise sum of exp(T_ij - 1) + diagonal T0 sum + finalize.
//   acc_ij = sum_k relu(hy[i,k] + hxb[j,k] + b1[k]) * W2[k]
//   sumExp += exp(acc_ij + b2 - 1);  if (i==j) sumT0 += acc_ij + b2
// Tile BI=128 x BJ=64, block 256 = 16(ty) x 16(tx), micro-tile 8x4.
// Last-finishing block (ticket) computes out[0] -> no k_fin kernel.
// ---------------------------------------------------------------------------
#define BI 128
#define BJ 64
#define STRD 44

__global__ __launch_bounds__(256) void k_pair(const float* __restrict__ hxb,
                                              const float* __restrict__ hy,
                                              const float* __restrict__ W2,
                                              const float* __restrict__ b1,
                                              const float* __restrict__ b2p,
                                              float* __restrict__ sums,
                                              float* __restrict__ out) {
    __shared__ float shy[BI * STRD];
    __shared__ float shx[BJ * STRD];
    __shared__ float sw2[STRD];
    __shared__ float red[8];

    const int tid = threadIdx.x;
    const int i0 = blockIdx.x * BI;
    const int j0 = blockIdx.y * BJ;

    for (int idx = tid; idx < BI * 10; idx += 256) {
        int rr = idx / 10, c = idx - rr * 10;
        float4 v = ((const float4*)(hy + (size_t)i0 * L))[idx];
        *(float4*)(shy + rr * STRD + c * 4) = v;
    }
    for (int idx = tid; idx < BJ * 10; idx += 256) {
        int rr = idx / 10, c = idx - rr * 10;
        float4 v = ((const float4*)(hxb + (size_t)j0 * L))[idx];
        float4 bv = ((const float4*)b1)[c];
        v.x += bv.x; v.y += bv.y; v.z += bv.z; v.w += bv.w;
        *(float4*)(shx + rr * STRD + c * 4) = v;
    }
    if (tid < 10) ((float4*)sw2)[tid] = ((const float4*)W2)[tid];
    __syncthreads();

    const int tx = tid & 15, ty = tid >> 4;

    float acc[8][4];
#pragma unroll
    for (int u = 0; u < 8; ++u)
#pragma unroll
        for (int v = 0; v < 4; ++v) acc[u][v] = 0.f;

#pragma unroll
    for (int k4 = 0; k4 < 10; ++k4) {
        float4 w = *(const float4*)(sw2 + k4 * 4);
        float4 ay[8], ax[4];
#pragma unroll
        for (int u = 0; u < 8; ++u)
            ay[u] = *(const float4*)(shy + (ty + 16 * u) * STRD + k4 * 4);
#pragma unroll
        for (int v = 0; v < 4; ++v)
            ax[v] = *(const float4*)(shx + (tx + 16 * v) * STRD + k4 * 4);
#pragma unroll
        for (int u = 0; u < 8; ++u)
#pragma unroll
            for (int v = 0; v < 4; ++v) {
                float t;
                t = ay[u].x + ax[v].x; t = fmaxf(t, 0.f); acc[u][v] += t * w.x;
                t = ay[u].y + ax[v].y; t = fmaxf(t, 0.f); acc[u][v] += t * w.y;
                t = ay[u].z + ax[v].z; t = fmaxf(t, 0.f); acc[u][v] += t * w.z;
                t = ay[u].w + ax[v].w; t = fmaxf(t, 0.f); acc[u][v] += t * w.w;
            }
    }

    const float b2v = b2p[0];
    float sumE = 0.f, sumT = 0.f;
#pragma unroll
    for (int u = 0; u < 8; ++u)
#pragma unroll
        for (int v = 0; v < 4; ++v) {
            int gi = i0 + ty + 16 * u;
            int gj = j0 + tx + 16 * v;
            float val = acc[u][v] + b2v;
            if (gi == gj) sumT += val;
            sumE += __expf(val - 1.f);
        }

#pragma unroll
    for (int off = 32; off > 0; off >>= 1) {
        sumE += __shfl_down(sumE, off);
        sumT += __shfl_down(sumT, off);
    }
    int wid = tid >> 6;
    if ((tid & 63) == 0) { red[wid] = sumE; red[4 + wid] = sumT; }
    __syncthreads();
    if (tid == 0) {
        float e = red[0] + red[1] + red[2] + red[3];
        float t = red[4] + red[5] + red[6] + red[7];
        atomicAdd(&sums[1], e);
        atomicAdd(&sums[0], t);
        __threadfence();
        unsigned done = atomicAdd(((unsigned*)sums) + 2, 1u);
        if (done == NPAIRBLK - 1) {
            float T = atomicAdd(&sums[0], 0.0f);   // coherent read-back
            float E = atomicAdd(&sums[1], 0.0f);
            const float invN = 1.0f / (float)NROWS;
            out[0] = T * invN - E * invN * invN;
        }
    }
}

extern "C" void kernel_launch(void* const* d_in, const int* in_sizes, int n_in,
                              void* d_out, int out_size, void* d_ws, size_t ws_size,
                              hipStream_t stream) {
    const float* x  = (const float*)d_in[0];
    const float* y  = (const float*)d_in[1];
    const float* W1 = (const float*)d_in[2];
    const float* b1 = (const float*)d_in[3];
    const float* W2 = (const float*)d_in[4];
    const float* b2 = (const float*)d_in[5];
    float* out = (float*)d_out;

    float* wsf  = (float*)d_ws;
    float* sums = wsf;                   // [0]=sumT0, [1]=sumExp, [2]=ticket
    float* hxb  = wsf + 16;              // 2048*40 (pure x-proj; b1 in k_pair)
    float* hy   = hxb + HN;              // 2048*40
    float* part = hy + HN;               // 8 * 40 * 4096 partials

    k_proj<<<dim3(64, NKC), 256, 0, stream>>>(x, y, W1, part);
    k_red<<<64, 256, 0, stream>>>(part, hxb, hy, sums);
    k_pair<<<dim3(NROWS / BI, NROWS / BJ), 256, 0, stream>>>(hxb, hy, W2, b1, b2,
                                                             sums, out);
}